// Round 2
// baseline (251.646 us; speedup 1.0000x reference)
//
#include <hip/hip_runtime.h>

#define NNODE 50000
#define NEDGE 600000
#define KDIN  239
#define DDIM  128
#define NTILES 3125           // 3125*16 == 50000 exactly
#define NBG   782             // one-shot gemm blocks: 782*4 waves >= 3125 tiles
#define NBUCK 256             // coarse dst buckets
#define BSZ   196             // dsts per bucket (196*256 >= 50000)
#define CHP   2344            // edges per hist/partition block (256*2344 >= 600000)
#define NXC   1563            // x->f16 convert blocks (32 rows each; 1563*32 >= 50000)

typedef _Float16 half8 __attribute__((ext_vector_type(8)));
typedef _Float16 half4 __attribute__((ext_vector_type(4)));
typedef __attribute__((ext_vector_type(4))) float f32x4;

__device__ __forceinline__ ushort f2h(float f){
  union { _Float16 h; ushort u; } c; c.h = (_Float16)f; return c.u;
}

// ---- prologue: coarse LDS histogram || weight transposes || x -> f16 [N][256] ----
__global__ __launch_bounds__(256) void pre_k(
    const float* __restrict__ x,
    const float* __restrict__ W_in, const float* __restrict__ W_gat, const float* __restrict__ W_h,
    ushort* __restrict__ BfA, ushort* __restrict__ BfB, ushort* __restrict__ BfC,
    ushort* __restrict__ xh,
    const int* __restrict__ ei, int* __restrict__ cpart)
{
  __shared__ int hb[NBUCK];
  const int b = blockIdx.x, t = threadIdx.x;
  if (b < NBUCK){                                  // coarse histogram, single sweep
    hb[t] = 0;
    __syncthreads();
    const int e0 = b*CHP, e1 = min(NEDGE, e0+CHP);
    for (int e=e0+t; e<e1; e+=256){
      int dst = min(max(ei[NEDGE+e],0), NNODE-1);
      atomicAdd(&hb[dst/BSZ], 1);                  // LDS atomic, 256 bins
    }
    __syncthreads();
    cpart[t*NBUCK + b] = hb[t];                    // bucket-major [bucket][block]
  } else if (b < NBUCK + 128){                     // W_in [239,128] -> BfA[n=128][k=256]
    int idx = (b-NBUCK)*256 + t; int n = idx >> 8, k = idx & 255;
    BfA[idx] = (k < KDIN) ? f2h(W_in[(size_t)k*DDIM + n]) : (ushort)0;
  } else if (b < NBUCK + 192){                     // W_gat -> BfB[n][128]
    int idx = (b-NBUCK-128)*256 + t; int n = idx >> 7, k = idx & 127;
    BfB[idx] = f2h(W_gat[(size_t)k*DDIM + n]);
  } else if (b < NBUCK + 256){                     // W_h -> BfC[n][128]
    int idx = (b-NBUCK-192)*256 + t; int n = idx >> 7, k = idx & 127;
    BfC[idx] = f2h(W_h[(size_t)k*DDIM + n]);
  } else {                                         // x fp32 -> xh f16 [N][256] (zero-pad)
    const int blk = b - (NBUCK + 256);             // 0..NXC-1, 32 rows per block
    const int r2 = t >> 7;                         // 0..1 (2 rows per iter)
    const int c2 = (t & 127) * 2;                  // even col
    #pragma unroll
    for (int it = 0; it < 16; ++it){
      const int row = blk*32 + it*2 + r2;
      if (row >= NNODE) continue;
      const float* __restrict__ xr = x + (size_t)row*KDIN;
      float v0 = (c2     < KDIN) ? xr[c2]   : 0.f; // coalesced dword reads
      float v1 = (c2 + 1 < KDIN) ? xr[c2+1] : 0.f;
      ushort2 o; o.x = f2h(v0); o.y = f2h(v1);
      *(ushort2*)(xh + (size_t)row*256 + c2) = o;  // coalesced 4B stores
    }
  }
}

// ---- one-shot MFMA GEMM: each wave computes ONE 16x128 tile ----
// AMODE 0: A = raw fp32 [M,239] (unused now); AMODE 1: A = f16 [M,Kpad]
// EPI 0: leaky(.01)(v+bias) -> f16
// EPI 1: v -> f16 + row dots os/od; per-tile maxes -> bms/bmd (NO contended atomics)
// EPI 2: h2=leaky(.01)(v+bias); y = h2@W_out + b_out -> outf fp32
// XW 1: block NBG runs the coarse scan (cpart counts -> write bases, in place)
// XW 2: blocks >= NBG run the single-sweep LDS-cursor partition into pairs[]
template<int KSTEPS, int EPI, int XW, int AMODE>
__global__ __launch_bounds__(256, 4) void gemm8_k(
    const float* __restrict__ Afp, const ushort* __restrict__ Af,
    const ushort* __restrict__ Btf, const float* __restrict__ bias,
    float* __restrict__ outf, ushort* __restrict__ outh,
    const float* __restrict__ vs, const float* __restrict__ vd,
    float* __restrict__ os, float* __restrict__ od,
    float* __restrict__ bms, float* __restrict__ bmd,
    const int* __restrict__ ei, int* __restrict__ cpart, int* __restrict__ pairs)
{
  constexpr int Kpad = KSTEPS*32;
  if (XW == 1 && blockIdx.x >= NBG){               // coarse scan, one block
    __shared__ int sc[NBUCK];
    const int t = threadIdx.x;                     // t = bucket id
    const int base = t*NBUCK;
    int sz = 0;
    for (int i=0;i<NBUCK;i++) sz += cpart[base+i]; // row sum (contiguous, L2-hot)
    sc[t] = sz;
    __syncthreads();
    #pragma unroll
    for (int off=1; off<NBUCK; off<<=1){           // Hillis-Steele inclusive scan
      int v = (t>=off) ? sc[t-off] : 0;
      __syncthreads();
      sc[t] += v;
      __syncthreads();
    }
    int run = sc[t] - sz;                          // exclusive: bucket base S[b]
    for (int i=0;i<NBUCK;i++){                     // counts -> per-(bucket,block) bases
      int c = cpart[base+i];
      cpart[base+i] = run;
      run += c;
    }
    return;
  }
  if (XW == 2 && blockIdx.x >= NBG){               // partition, single sweep
    __shared__ int cur[NBUCK];
    const int pb = blockIdx.x - NBG;
    cur[threadIdx.x] = cpart[threadIdx.x*NBUCK + pb];
    __syncthreads();
    const int e0 = pb*CHP, e1 = min(NEDGE, e0+CHP);
    for (int e=e0+threadIdx.x; e<e1; e+=256){
      int dst = min(max(ei[NEDGE+e],0), NNODE-1);
      int src = min(max(ei[e],0), NNODE-1);
      int bk = (unsigned)dst / BSZ;
      int pos = atomicAdd(&cur[bk], 1);            // LDS atomic
      pairs[pos] = src | ((dst - bk*BSZ) << 16);   // mostly-contiguous sub-range stores
    }
    return;
  }
  // ---- one-shot gemm path ----
  const int lane = threadIdx.x & 63;
  const int wave = threadIdx.x >> 6;
  const int q = lane >> 4, c = lane & 15;
  const int tile = blockIdx.x*4 + wave;
  if (tile >= NTILES) return;
  const int rowBase = tile*16;
  const int arow = rowBase + c;                    // always < NNODE (3125*16 exact)
  half8 af[KSTEPS];
  if (AMODE == 0){
    const float* __restrict__ ap = Afp + (size_t)arow*KDIN;
    #pragma unroll
    for (int s=0;s<KSTEPS;s++){
      #pragma unroll
      for (int i=0;i<8;i++){
        const int k = s*32 + q*8 + i;
        af[s][i] = (_Float16)((k < KDIN) ? ap[k] : 0.f);
      }
    }
  } else {
    const ushort* __restrict__ ap = Af + (size_t)arow*Kpad + q*8;
    #pragma unroll
    for (int s=0;s<KSTEPS;s++) af[s] = *(const half8*)(ap + s*32); // aligned 16B loads
  }
  f32x4 acc[8];
  #pragma unroll
  for (int t=0;t<8;t++) acc[t] = (f32x4){0.f,0.f,0.f,0.f};
  #pragma unroll
  for (int s=0;s<KSTEPS;s++){
    #pragma unroll
    for (int t=0;t<8;t++){
      const half8 bf = *(const half8*)(Btf + (size_t)(16*t + c)*Kpad + s*32 + q*8);
      acc[t] = __builtin_amdgcn_mfma_f32_16x16x32_f16(af[s], bf, acc[t], 0,0,0);
    }
  }
  // epilogue: C/D layout col=lane&15, row=(lane>>4)*4+reg  [m89/m91-verified]
  float pr0[4] = {0,0,0,0}, pr1[4] = {0,0,0,0};
  #pragma unroll
  for (int t=0;t<8;t++){
    const int col = 16*t + c;
    const float bv = (EPI != 1) ? bias[col] : 0.f;
    float va=0.f, vb=0.f;
    if (EPI == 1){ va = vs[col]; vb = vd[col]; }
    if (EPI == 2){ va = vs[2*col]; vb = vs[2*col+1]; }
    #pragma unroll
    for (int r=0;r<4;r++){
      const int row = rowBase + q*4 + r;
      float v = acc[t][r] + bv;
      if (EPI != 1) v = (v >= 0.f) ? v : 0.01f*v;
      if (EPI == 0){
        outh[(size_t)row*DDIM + col] = f2h(v);
      } else if (EPI == 1){
        outh[(size_t)row*DDIM + col] = f2h(v);
        pr0[r] += v*va; pr1[r] += v*vb;
      } else {
        pr0[r] += v*va; pr1[r] += v*vb;
      }
    }
  }
  if (EPI >= 1){
    float lmax_s = -3.0e38f, lmax_d = -3.0e38f;
    #pragma unroll
    for (int r=0;r<4;r++){
      float s0 = pr0[r], s1 = pr1[r];
      s0 += __shfl_xor(s0,8); s1 += __shfl_xor(s1,8);
      s0 += __shfl_xor(s0,4); s1 += __shfl_xor(s1,4);
      s0 += __shfl_xor(s0,2); s1 += __shfl_xor(s1,2);
      s0 += __shfl_xor(s0,1); s1 += __shfl_xor(s1,1);
      if (EPI == 1){ lmax_s = fmaxf(lmax_s, s0); lmax_d = fmaxf(lmax_d, s1); }
      if (c == 0){
        const int row = rowBase + q*4 + r;
        if (EPI == 1){ os[row] = s0; od[row] = s1; }
        else { float2 y2; y2.x = s0 + vd[0]; y2.y = s1 + vd[1];
               *(float2*)&outf[(size_t)row*2] = y2; }
      }
    }
    if (EPI == 1){
      #pragma unroll
      for (int off=32; off>0; off>>=1){
        lmax_s = fmaxf(lmax_s, __shfl_xor(lmax_s, off));
        lmax_d = fmaxf(lmax_d, __shfl_xor(lmax_d, off));
      }
      // per-tile max pair, disjoint addresses -> no TCC same-line serialization
      if (lane == 0){ bms[tile] = lmax_s; bmd[tile] = lmax_d; }
    }
  }
}

// ---- fine CSR within one bucket: hist(196) + scan + scatter; emits offs/degv/es ----
// block NBUCK: tree-reduce per-tile maxes (bms/bmd) -> gmf[0..1] (runs before agg_k)
__global__ __launch_bounds__(256) void fine_k(const int* __restrict__ pairs,
    const int* __restrict__ cpart, int* __restrict__ offs, int* __restrict__ degv,
    int* __restrict__ es, const float* __restrict__ bms, const float* __restrict__ bmd,
    float* __restrict__ gmf)
{
  __shared__ int fh[256];
  __shared__ int sc[256];
  const int b = blockIdx.x, t = threadIdx.x;
  if (b == NBUCK){                                 // global max reduce, one block
    float ms = -3.0e38f, md = -3.0e38f;
    for (int i=t; i<NTILES; i+=256){ ms = fmaxf(ms, bms[i]); md = fmaxf(md, bmd[i]); }
    #pragma unroll
    for (int off=32; off>0; off>>=1){
      ms = fmaxf(ms, __shfl_xor(ms, off));
      md = fmaxf(md, __shfl_xor(md, off));
    }
    float* red = (float*)fh;
    const int w = t >> 6;
    if ((t & 63) == 0){ red[w] = ms; red[4+w] = md; }
    __syncthreads();
    if (t == 0){
      gmf[0] = fmaxf(fmaxf(red[0],red[1]), fmaxf(red[2],red[3]));
      gmf[1] = fmaxf(fmaxf(red[4],red[5]), fmaxf(red[6],red[7]));
    }
    return;
  }
  const int s0 = cpart[b*NBUCK];                   // bucket base S[b] (post-scan cpart)
  const int s1 = (b < NBUCK-1) ? cpart[(b+1)*NBUCK] : NEDGE;
  fh[t] = 0;
  __syncthreads();
  for (int i=s0+t; i<s1; i+=256)                   // contiguous, L2-hot
    atomicAdd(&fh[pairs[i] >> 16], 1);
  __syncthreads();
  const int deg = fh[t];
  sc[t] = deg;
  __syncthreads();
  #pragma unroll
  for (int off=1; off<256; off<<=1){               // inclusive scan
    int v = (t>=off) ? sc[t-off] : 0;
    __syncthreads();
    sc[t] += v;
    __syncthreads();
  }
  const int excl = sc[t] - deg;
  const int dst = b*BSZ + t;
  if (t < BSZ && dst < NNODE){ offs[dst] = s0 + excl; degv[dst] = deg; }
  fh[t] = s0 + excl;                               // becomes cursor
  __syncthreads();
  for (int i=s0+t; i<s1; i+=256){
    const int p = pairs[i];
    const int pos = atomicAdd(&fh[p >> 16], 1);    // LDS atomic
    es[pos] = p & 0xFFFF;                          // src (<50000 fits 16 bits)
  }
}

// ---- fused softmax+gather: og = softmax-agg(g f16)+b_gat ----
__global__ __launch_bounds__(256) void agg_k(const ushort* __restrict__ gf,
    const int* __restrict__ offs, const int* __restrict__ degv,
    const int* __restrict__ es,
    const float* __restrict__ a_src, const float* __restrict__ a_dst,
    const float* __restrict__ gmf, const float* __restrict__ b_gat,
    ushort* __restrict__ og)
{
  const int lane = threadIdx.x & 63;
  const int half = lane >> 5, li = lane & 31;
  const int dst = blockIdx.x*8 + (threadIdx.x >> 6)*2 + half;
  if (dst >= NNODE) return;
  float M = gmf[0] + gmf[1];
  M = (M >= 0.f) ? M : 0.2f*M;
  const int start = offs[dst];
  const int deg = degv[dst];
  const int* __restrict__ bin = es + start;
  const float ad = a_dst[dst];
  f32x4 a0={0,0,0,0}, a1={0,0,0,0}, a2={0,0,0,0}, a3={0,0,0,0};
  float w0s=0.f, w1s=0.f, w2s=0.f, w3s=0.f;
  int j = 0;
  for (; j+3 < deg; j += 4){
    const int i0=bin[j], i1=bin[j+1], i2=bin[j+2], i3=bin[j+3];
    float e0=a_src[i0]+ad; e0=(e0>=0.f)?e0:0.2f*e0;
    float e1=a_src[i1]+ad; e1=(e1>=0.f)?e1:0.2f*e1;
    float e2=a_src[i2]+ad; e2=(e2>=0.f)?e2:0.2f*e2;
    float e3=a_src[i3]+ad; e3=(e3>=0.f)?e3:0.2f*e3;
    const float w0=__expf(e0-M), w1=__expf(e1-M), w2=__expf(e2-M), w3=__expf(e3-M);
    const half4 g0 = *(const half4*)(gf + (size_t)i0*DDIM + li*4);
    const half4 g1 = *(const half4*)(gf + (size_t)i1*DDIM + li*4);
    const half4 g2 = *(const half4*)(gf + (size_t)i2*DDIM + li*4);
    const half4 g3 = *(const half4*)(gf + (size_t)i3*DDIM + li*4);
    #pragma unroll
    for (int i=0;i<4;i++){
      a0[i] += w0*(float)g0[i]; a1[i] += w1*(float)g1[i];
      a2[i] += w2*(float)g2[i]; a3[i] += w3*(float)g3[i];
    }
    w0s += w0; w1s += w1; w2s += w2; w3s += w3;
  }
  for (; j < deg; ++j){
    const int si = bin[j];
    float e0=a_src[si]+ad; e0=(e0>=0.f)?e0:0.2f*e0;
    const float w = __expf(e0-M);
    const half4 gv = *(const half4*)(gf + (size_t)si*DDIM + li*4);
    #pragma unroll
    for (int i=0;i<4;i++) a0[i] += w*(float)gv[i];
    w0s += w;
  }
  {                                                // self-loop (unconditional)
    float evs=a_src[dst]+ad; evs=(evs>=0.f)?evs:0.2f*evs;
    const float w = __expf(evs-M);
    const half4 gv = *(const half4*)(gf + (size_t)dst*DDIM + li*4);
    #pragma unroll
    for (int i=0;i<4;i++) a0[i] += w*(float)gv[i];
    w0s += w;
  }
  const float inv = 1.f/(w0s+w1s+w2s+w3s);         // >= w_self > 0
  const float4 bg = *(const float4*)&b_gat[li*4];
  ushort4 o;
  o.x = f2h((a0[0]+a1[0]+a2[0]+a3[0])*inv + bg.x);
  o.y = f2h((a0[1]+a1[1]+a2[1]+a3[1])*inv + bg.y);
  o.z = f2h((a0[2]+a1[2]+a2[2]+a3[2])*inv + bg.z);
  o.w = f2h((a0[3]+a1[3]+a2[3]+a3[3])*inv + bg.w);
  *(ushort4*)(og + (size_t)dst*DDIM + li*4) = o;
}

extern "C" void kernel_launch(void* const* d_in, const int* in_sizes, int n_in,
                              void* d_out, int out_size, void* d_ws, size_t ws_size,
                              hipStream_t stream)
{
  const float* x       = (const float*)d_in[0];
  const int*   ei      = (const int*)d_in[1];
  // d_in[2] = edge_type (unused by reference)
  const float* W_in    = (const float*)d_in[3];
  const float* b_in    = (const float*)d_in[4];
  const float* W_gat   = (const float*)d_in[5];
  const float* att_src = (const float*)d_in[6];
  const float* att_dst = (const float*)d_in[7];
  const float* b_gat   = (const float*)d_in[8];
  const float* W_h     = (const float*)d_in[9];
  const float* b_h     = (const float*)d_in[10];
  const float* W_out   = (const float*)d_in[11];
  const float* b_out   = (const float*)d_in[12];

  // workspace (~51.8 MB). xh (dead after step 2) overlays all step>=3-born buffers.
  char* ws = (char*)d_ws;
  ushort*   hf     = (ushort*)  (ws + 0);          // h f16 [N,128]    12.8 MB  (steps 2-3)
  ushort*   gf     = (ushort*)  (ws + 12800000);   // g f16 [N,128]    12.8 MB  (steps 3-5)
  ushort*   xh     = (ushort*)  (ws + 25600000);   // x f16 [N,256]    25.6 MB  (steps 1-2)
  // ---- overlay region (all born step>=3, after xh is dead) ----
  ushort*   og     = (ushort*)  (ws + 25600000);   // og f16 [N,128]   12.8 MB  (steps 5-6)
  int*      pairs  = (int*)     (ws + 38400000);   // packed edges      2.4 MB  (steps 3-4)
  int*      es     = (int*)     (ws + 40800000);   // CSR src           2.4 MB  (steps 4-5)
  int*      offs   = (int*)     (ws + 43200000);   // 200 KB                    (steps 4-5)
  int*      degv   = (int*)     (ws + 43400000);   // 200 KB                    (steps 4-5)
  float*    a_src  = (float*)   (ws + 43600000);   // 200 KB                    (steps 3-5)
  float*    a_dst  = (float*)   (ws + 43800000);   // 200 KB                    (steps 3-5)
  float*    bmaxS  = (float*)   (ws + 44000000);   // per-tile maxes 12.5 KB    (steps 3-4)
  float*    bmaxD  = (float*)   (ws + 44016000);   // 12.5 KB                   (steps 3-4)
  // ---- end overlay (region ends at 51.2 MB) ----
  ushort*   BfA    = (ushort*)  (ws + 51200000);   // 128 KB  (steps 1-2)
  ushort*   BfB    = (ushort*)  (ws + 51400000);   // 32 KB   (steps 1-3)
  ushort*   BfC    = (ushort*)  (ws + 51440000);   // 32 KB   (steps 1-6)
  int*      cpart  = (int*)     (ws + 51480000);   // [256][256], 256 KB (steps 1-4)
  float*    gm     = (float*)   (ws + 51750000);   // [gmax_s, gmax_d]   (steps 4-5)

  // 1: coarse histogram || weight transposes || x -> f16 (coalesced convert)
  pre_k<<<NBUCK + 256 + NXC, 256, 0, stream>>>(x, W_in, W_gat, W_h,
      BfA, BfB, BfC, xh, ei, cpart);
  // 2: gemmA (h = leaky(xh@W_in+b_in) -> f16, vectorized f16 A loads) || coarse scan (1 block)
  gemm8_k<8,0,1,1><<<NBG + 1, 256, 0, stream>>>(nullptr, xh, BfA, b_in,
      nullptr, hf, nullptr, nullptr, nullptr, nullptr, nullptr, nullptr, nullptr, cpart, nullptr);
  // 3: gemmB (g = h@W_gat -> f16 + a_src/a_dst + per-tile maxes) || bucket partition (256 blocks)
  gemm8_k<4,1,2,1><<<NBG + NBUCK, 256, 0, stream>>>(nullptr, hf, BfB, nullptr,
      nullptr, gf, att_src, att_dst, a_src, a_dst, bmaxS, bmaxD, ei, cpart, pairs);
  // 4: fine CSR per bucket (offs/degv/es) || global max reduce (1 block)
  fine_k<<<NBUCK + 1, 256, 0, stream>>>(pairs, cpart, offs, degv, es, bmaxS, bmaxD, gm);
  // 5: fused softmax + gather + normalize
  agg_k<<<6250, 256, 0, stream>>>(gf, offs, degv, es, a_src, a_dst, gm, b_gat, og);
  // 6: gemmC: y = leaky(og@W_h + b_h) @ W_out + b_out -> d_out fp32
  gemm8_k<4,2,0,1><<<NBG, 256, 0, stream>>>(nullptr, og, BfC, b_h,
      (float*)d_out, nullptr, W_out, b_out, nullptr, nullptr, nullptr, nullptr, nullptr, nullptr, nullptr);
}

// Round 3
// 181.403 us; speedup vs baseline: 1.3872x; 1.3872x over previous
//
#include <hip/hip_runtime.h>

#define NNODE 50000
#define NEDGE 600000
#define KDIN  239
#define DDIM  128
#define NTILES 3125           // 3125*16 == 50000 exactly
#define NBG   782             // one-shot gemm blocks: 782*4 waves >= 3125 tiles
#define NBUCK 256             // coarse dst buckets
#define BSZ   196             // dsts per bucket (196*256 >= 50000)
#define NPB   128             // partition/hist blocks
#define CHP   4688            // edges per hist/partition block (128*4688 >= 600000)

typedef _Float16 half8 __attribute__((ext_vector_type(8)));
typedef _Float16 half4 __attribute__((ext_vector_type(4)));
typedef __attribute__((ext_vector_type(4))) float f32x4;

__device__ __forceinline__ ushort f2h(float f){
  union { _Float16 h; ushort u; } c; c.h = (_Float16)f; return c.u;
}

// ---- prologue: coarse LDS histogram (block-major cpart) || weight transposes ----
__global__ __launch_bounds__(256) void pre_k(
    const float* __restrict__ W_in, const float* __restrict__ W_gat, const float* __restrict__ W_h,
    ushort* __restrict__ BfA, ushort* __restrict__ BfB, ushort* __restrict__ BfC,
    const int* __restrict__ ei, int* __restrict__ cpart)
{
  __shared__ int hb[NBUCK];
  const int b = blockIdx.x, t = threadIdx.x;
  if (b < NPB){                                    // coarse histogram, single sweep
    hb[t] = 0;
    __syncthreads();
    const int e0 = b*CHP, e1 = min(NEDGE, e0+CHP);
    for (int e=e0+t; e<e1; e+=256){
      int dst = min(max(ei[NEDGE+e],0), NNODE-1);
      atomicAdd(&hb[dst/BSZ], 1);                  // LDS atomic, 256 bins
    }
    __syncthreads();
    cpart[b*NBUCK + t] = hb[t];                    // block-major: coalesced write
  } else if (b < NPB + 128){                       // W_in [239,128] -> BfA[n=128][k=256]
    int idx = (b-NPB)*256 + t; int n = idx >> 8, k = idx & 255;
    BfA[idx] = (k < KDIN) ? f2h(W_in[(size_t)k*DDIM + n]) : (ushort)0;
  } else if (b < NPB + 192){                       // W_gat -> BfB[n][128]
    int idx = (b-NPB-128)*256 + t; int n = idx >> 7, k = idx & 127;
    BfB[idx] = f2h(W_gat[(size_t)k*DDIM + n]);
  } else {                                         // W_h -> BfC[n][128]
    int idx = (b-NPB-192)*256 + t; int n = idx >> 7, k = idx & 127;
    BfC[idx] = f2h(W_h[(size_t)k*DDIM + n]);
  }
}

// ---- one-shot MFMA GEMM: each wave computes ONE 16x128 tile; B staged in LDS ----
// AMODE 0: A = raw fp32 [M,239]; AMODE 1: A = f16 [M,Kpad]
// EPI 0: leaky(.01)(v+bias) -> f16
// EPI 1: v -> f16 + row dots os/od; per-tile maxes -> bms/bmd
// EPI 2: h2=leaky(.01)(v+bias); y = h2@W_out + b_out -> outf fp32
// XW 1: block NBG runs the bucket scan (coalesced column passes over cpart)
// XW 2: blocks >= NBG run the single-sweep LDS-cursor partition into pairs[]
template<int KSTEPS, int EPI, int XW, int AMODE>
__global__ __launch_bounds__(256, 4) void gemm8_k(
    const float* __restrict__ Afp, const ushort* __restrict__ Af,
    const ushort* __restrict__ Btf, const float* __restrict__ bias,
    float* __restrict__ outf, ushort* __restrict__ outh,
    const float* __restrict__ vs, const float* __restrict__ vd,
    float* __restrict__ os, float* __restrict__ od,
    float* __restrict__ bms, float* __restrict__ bmd,
    const int* __restrict__ ei, int* __restrict__ cpart, int* __restrict__ pairs)
{
  constexpr int Kpad = KSTEPS*32;
  constexpr int Kb   = Kpad*2;                     // row bytes in Btf/Bs
  if (XW == 1 && blockIdx.x >= NBG){               // bucket scan, one block (coalesced)
    __shared__ int sc[NBUCK];
    const int t = threadIdx.x;                     // t = bucket id
    int tot = 0;
    #pragma unroll 8
    for (int i=0;i<NPB;i++) tot += cpart[i*NBUCK + t];   // coalesced column sum
    sc[t] = tot;
    __syncthreads();
    #pragma unroll
    for (int off=1; off<NBUCK; off<<=1){           // Hillis-Steele inclusive scan
      int v = (t>=off) ? sc[t-off] : 0;
      __syncthreads();
      sc[t] += v;
      __syncthreads();
    }
    int run = sc[t] - tot;                         // exclusive: bucket base S[t]
    #pragma unroll 8
    for (int i=0;i<NPB;i++){                       // counts -> per-(block,bucket) bases
      int c = cpart[i*NBUCK + t];
      cpart[i*NBUCK + t] = run;                    // coalesced rewrite; row 0 == S[t]
      run += c;
    }
    return;
  }
  if (XW == 2 && blockIdx.x >= NBG){               // partition, single sweep
    __shared__ int cur[NBUCK];
    const int pb = blockIdx.x - NBG;
    cur[threadIdx.x] = cpart[pb*NBUCK + threadIdx.x];    // coalesced init
    __syncthreads();
    const int e0 = pb*CHP, e1 = min(NEDGE, e0+CHP);
    for (int e=e0+threadIdx.x; e<e1; e+=256){
      int dst = min(max(ei[NEDGE+e],0), NNODE-1);
      int src = min(max(ei[e],0), NNODE-1);
      int bk = (unsigned)dst / BSZ;
      int pos = atomicAdd(&cur[bk], 1);            // LDS atomic
      pairs[pos] = src | ((dst - bk*BSZ) << 16);   // mostly-contiguous sub-range stores
    }
    return;
  }
  // ---- one-shot gemm path ----
  // cooperative B stage: [128][Kpad] f16, XOR-swizzled (byte ^= (row&7)<<4)
  __shared__ __attribute__((aligned(16))) ushort Bs[128*Kpad];
  {
    constexpr int CH = (128*Kb)/16;                // 16B chunks (4096 or 2048)
    #pragma unroll
    for (int it=0; it<CH/256; ++it){
      const int idx = it*256 + threadIdx.x;
      const int row = (idx*16)/Kb, sl = (idx*16)%Kb;
      const half8 v = *(const half8*)(Btf + (size_t)idx*8);     // coalesced 16B
      *(half8*)((char*)Bs + row*Kb + (sl ^ ((row&7)<<4))) = v;
    }
  }
  __syncthreads();
  const int lane = threadIdx.x & 63;
  const int wave = threadIdx.x >> 6;
  const int q = lane >> 4, c = lane & 15;
  const int tile = blockIdx.x*4 + wave;
  if (tile >= NTILES) return;                      // after the barrier: safe
  const int rowBase = tile*16;
  const int arow = rowBase + c;                    // always < NNODE (3125*16 exact)
  half8 af[KSTEPS];
  if (AMODE == 0){
    const float* __restrict__ ap = Afp + (size_t)arow*KDIN;
    #pragma unroll
    for (int s=0;s<KSTEPS-1;s++){                  // k = s*32+q*8+i <= 223 < 239: no guard
      const float* __restrict__ p = ap + s*32 + q*8;
      #pragma unroll
      for (int i=0;i<8;i++) af[s][i] = (_Float16)p[i];
    }
    {                                              // last step: guarded tail
      const int s = KSTEPS-1;
      #pragma unroll
      for (int i=0;i<8;i++){
        const int k = s*32 + q*8 + i;
        af[s][i] = (_Float16)((k < KDIN) ? ap[k] : 0.f);
      }
    }
  } else {
    const ushort* __restrict__ ap = Af + (size_t)arow*Kpad + q*8;
    #pragma unroll
    for (int s=0;s<KSTEPS;s++) af[s] = *(const half8*)(ap + s*32); // aligned 16B loads
  }
  f32x4 acc[8];
  #pragma unroll
  for (int t=0;t<8;t++) acc[t] = (f32x4){0.f,0.f,0.f,0.f};
  const int swz = (c&7)<<4;
  const char* __restrict__ bsl = (const char*)Bs + c*Kb;
  #pragma unroll
  for (int s=0;s<KSTEPS;s++){
    const int so = (s*64 + q*16) ^ swz;
    #pragma unroll
    for (int t=0;t<8;t++){
      const half8 bf = *(const half8*)(bsl + t*16*Kb + so);      // ds_read_b128
      acc[t] = __builtin_amdgcn_mfma_f32_16x16x32_f16(af[s], bf, acc[t], 0,0,0);
    }
  }
  // epilogue: C/D layout col=lane&15, row=(lane>>4)*4+reg  [m89/m91-verified]
  float pr0[4] = {0,0,0,0}, pr1[4] = {0,0,0,0};
  #pragma unroll
  for (int t=0;t<8;t++){
    const int col = 16*t + c;
    const float bv = (EPI != 1) ? bias[col] : 0.f;
    float va=0.f, vb=0.f;
    if (EPI == 1){ va = vs[col]; vb = vd[col]; }
    if (EPI == 2){ va = vs[2*col]; vb = vs[2*col+1]; }
    #pragma unroll
    for (int r=0;r<4;r++){
      const int row = rowBase + q*4 + r;
      float v = acc[t][r] + bv;
      if (EPI != 1) v = (v >= 0.f) ? v : 0.01f*v;
      if (EPI == 0){
        outh[(size_t)row*DDIM + col] = f2h(v);
      } else if (EPI == 1){
        outh[(size_t)row*DDIM + col] = f2h(v);
        pr0[r] += v*va; pr1[r] += v*vb;
      } else {
        pr0[r] += v*va; pr1[r] += v*vb;
      }
    }
  }
  if (EPI >= 1){
    float lmax_s = -3.0e38f, lmax_d = -3.0e38f;
    #pragma unroll
    for (int r=0;r<4;r++){
      float s0 = pr0[r], s1 = pr1[r];
      s0 += __shfl_xor(s0,8); s1 += __shfl_xor(s1,8);
      s0 += __shfl_xor(s0,4); s1 += __shfl_xor(s1,4);
      s0 += __shfl_xor(s0,2); s1 += __shfl_xor(s1,2);
      s0 += __shfl_xor(s0,1); s1 += __shfl_xor(s1,1);
      if (EPI == 1){ lmax_s = fmaxf(lmax_s, s0); lmax_d = fmaxf(lmax_d, s1); }
      if (c == 0){
        const int row = rowBase + q*4 + r;
        if (EPI == 1){ os[row] = s0; od[row] = s1; }
        else { float2 y2; y2.x = s0 + vd[0]; y2.y = s1 + vd[1];
               *(float2*)&outf[(size_t)row*2] = y2; }
      }
    }
    if (EPI == 1){
      #pragma unroll
      for (int off=32; off>0; off>>=1){
        lmax_s = fmaxf(lmax_s, __shfl_xor(lmax_s, off));
        lmax_d = fmaxf(lmax_d, __shfl_xor(lmax_d, off));
      }
      // per-tile max pair, disjoint addresses -> no TCC same-line serialization
      if (lane == 0){ bms[tile] = lmax_s; bmd[tile] = lmax_d; }
    }
  }
}

// ---- fine CSR within one bucket: hist(196) + scan + scatter; emits offs/degv/es ----
// block NBUCK: tree-reduce per-tile maxes (bms/bmd) -> gmf[0..1] (runs before agg_k)
__global__ __launch_bounds__(256) void fine_k(const int* __restrict__ pairs,
    const int* __restrict__ cpart, int* __restrict__ offs, int* __restrict__ degv,
    int* __restrict__ es, const float* __restrict__ bms, const float* __restrict__ bmd,
    float* __restrict__ gmf)
{
  __shared__ int fh[256];
  __shared__ int sc[256];
  const int b = blockIdx.x, t = threadIdx.x;
  if (b == NBUCK){                                 // global max reduce, one block
    float ms = -3.0e38f, md = -3.0e38f;
    for (int i=t; i<NTILES; i+=256){ ms = fmaxf(ms, bms[i]); md = fmaxf(md, bmd[i]); }
    #pragma unroll
    for (int off=32; off>0; off>>=1){
      ms = fmaxf(ms, __shfl_xor(ms, off));
      md = fmaxf(md, __shfl_xor(md, off));
    }
    float* red = (float*)fh;
    const int w = t >> 6;
    if ((t & 63) == 0){ red[w] = ms; red[4+w] = md; }
    __syncthreads();
    if (t == 0){
      gmf[0] = fmaxf(fmaxf(red[0],red[1]), fmaxf(red[2],red[3]));
      gmf[1] = fmaxf(fmaxf(red[4],red[5]), fmaxf(red[6],red[7]));
    }
    return;
  }
  const int s0 = cpart[b];                         // S[b] = cpart[block 0][bucket b]
  const int s1 = (b < NBUCK-1) ? cpart[b+1] : NEDGE;
  fh[t] = 0;
  __syncthreads();
  for (int i=s0+t; i<s1; i+=256)                   // contiguous, L2-hot
    atomicAdd(&fh[pairs[i] >> 16], 1);
  __syncthreads();
  const int deg = fh[t];
  sc[t] = deg;
  __syncthreads();
  #pragma unroll
  for (int off=1; off<256; off<<=1){               // inclusive scan
    int v = (t>=off) ? sc[t-off] : 0;
    __syncthreads();
    sc[t] += v;
    __syncthreads();
  }
  const int excl = sc[t] - deg;
  const int dst = b*BSZ + t;
  if (t < BSZ && dst < NNODE){ offs[dst] = s0 + excl; degv[dst] = deg; }
  fh[t] = s0 + excl;                               // becomes cursor
  __syncthreads();
  for (int i=s0+t; i<s1; i+=256){
    const int p = pairs[i];
    const int pos = atomicAdd(&fh[p >> 16], 1);    // LDS atomic
    es[pos] = p & 0xFFFF;                          // src (<50000 fits 16 bits)
  }
}

// ---- fused softmax+gather: og = softmax-agg(g f16)+b_gat ----
__global__ __launch_bounds__(256) void agg_k(const ushort* __restrict__ gf,
    const int* __restrict__ offs, const int* __restrict__ degv,
    const int* __restrict__ es,
    const float* __restrict__ a_src, const float* __restrict__ a_dst,
    const float* __restrict__ gmf, const float* __restrict__ b_gat,
    ushort* __restrict__ og)
{
  const int lane = threadIdx.x & 63;
  const int half = lane >> 5, li = lane & 31;
  const int dst = blockIdx.x*8 + (threadIdx.x >> 6)*2 + half;
  if (dst >= NNODE) return;
  float M = gmf[0] + gmf[1];
  M = (M >= 0.f) ? M : 0.2f*M;
  const int start = offs[dst];
  const int deg = degv[dst];
  const int* __restrict__ bin = es + start;
  const float ad = a_dst[dst];
  f32x4 a0={0,0,0,0}, a1={0,0,0,0}, a2={0,0,0,0}, a3={0,0,0,0};
  float w0s=0.f, w1s=0.f, w2s=0.f, w3s=0.f;
  int j = 0;
  for (; j+3 < deg; j += 4){
    const int i0=bin[j], i1=bin[j+1], i2=bin[j+2], i3=bin[j+3];
    float e0=a_src[i0]+ad; e0=(e0>=0.f)?e0:0.2f*e0;
    float e1=a_src[i1]+ad; e1=(e1>=0.f)?e1:0.2f*e1;
    float e2=a_src[i2]+ad; e2=(e2>=0.f)?e2:0.2f*e2;
    float e3=a_src[i3]+ad; e3=(e3>=0.f)?e3:0.2f*e3;
    const float w0=__expf(e0-M), w1=__expf(e1-M), w2=__expf(e2-M), w3=__expf(e3-M);
    const half4 g0 = *(const half4*)(gf + (size_t)i0*DDIM + li*4);
    const half4 g1 = *(const half4*)(gf + (size_t)i1*DDIM + li*4);
    const half4 g2 = *(const half4*)(gf + (size_t)i2*DDIM + li*4);
    const half4 g3 = *(const half4*)(gf + (size_t)i3*DDIM + li*4);
    #pragma unroll
    for (int i=0;i<4;i++){
      a0[i] += w0*(float)g0[i]; a1[i] += w1*(float)g1[i];
      a2[i] += w2*(float)g2[i]; a3[i] += w3*(float)g3[i];
    }
    w0s += w0; w1s += w1; w2s += w2; w3s += w3;
  }
  for (; j < deg; ++j){
    const int si = bin[j];
    float e0=a_src[si]+ad; e0=(e0>=0.f)?e0:0.2f*e0;
    const float w = __expf(e0-M);
    const half4 gv = *(const half4*)(gf + (size_t)si*DDIM + li*4);
    #pragma unroll
    for (int i=0;i<4;i++) a0[i] += w*(float)gv[i];
    w0s += w;
  }
  {                                                // self-loop (unconditional)
    float evs=a_src[dst]+ad; evs=(evs>=0.f)?evs:0.2f*evs;
    const float w = __expf(evs-M);
    const half4 gv = *(const half4*)(gf + (size_t)dst*DDIM + li*4);
    #pragma unroll
    for (int i=0;i<4;i++) a0[i] += w*(float)gv[i];
    w0s += w;
  }
  const float inv = 1.f/(w0s+w1s+w2s+w3s);         // >= w_self > 0
  const float4 bg = *(const float4*)&b_gat[li*4];
  ushort4 o;
  o.x = f2h((a0[0]+a1[0]+a2[0]+a3[0])*inv + bg.x);
  o.y = f2h((a0[1]+a1[1]+a2[1]+a3[1])*inv + bg.y);
  o.z = f2h((a0[2]+a1[2]+a2[2]+a3[2])*inv + bg.z);
  o.w = f2h((a0[3]+a1[3]+a2[3]+a3[3])*inv + bg.w);
  *(ushort4*)(og + (size_t)dst*DDIM + li*4) = o;
}

extern "C" void kernel_launch(void* const* d_in, const int* in_sizes, int n_in,
                              void* d_out, int out_size, void* d_ws, size_t ws_size,
                              hipStream_t stream)
{
  const float* x       = (const float*)d_in[0];
  const int*   ei      = (const int*)d_in[1];
  // d_in[2] = edge_type (unused by reference)
  const float* W_in    = (const float*)d_in[3];
  const float* b_in    = (const float*)d_in[4];
  const float* W_gat   = (const float*)d_in[5];
  const float* att_src = (const float*)d_in[6];
  const float* att_dst = (const float*)d_in[7];
  const float* b_gat   = (const float*)d_in[8];
  const float* W_h     = (const float*)d_in[9];
  const float* b_h     = (const float*)d_in[10];
  const float* W_out   = (const float*)d_in[11];
  const float* b_out   = (const float*)d_in[12];

  // workspace (~45 MB):
  char* ws = (char*)d_ws;
  ushort*   hf     = (ushort*)  (ws + 0);          // h f16 [N,128]    12.8 MB
  ushort*   gf     = (ushort*)  (ws + 12800000);   // g f16 [N,128]    12.8 MB
  ushort*   og     = (ushort*)  (ws + 25600000);   // og f16 [N,128]   12.8 MB
  ushort*   BfA    = (ushort*)  (ws + 38400000);   // 128 KB
  ushort*   BfB    = (ushort*)  (ws + 38600000);   // 32 KB
  ushort*   BfC    = (ushort*)  (ws + 38700000);   // 32 KB
  int*      cpart  = (int*)     (ws + 38800000);   // [NPB][256] counts->bases, 128 KB
  int*      pairs  = (int*)     (ws + 39100000);   // bucket-major packed edges, 2.4 MB
  int*      es     = (int*)     (ws + 41500000);   // CSR src, 2.4 MB
  int*      offs   = (int*)     (ws + 43900000);   // 200 KB
  int*      degv   = (int*)     (ws + 44100000);   // 200 KB
  float*    a_src  = (float*)   (ws + 44300000);
  float*    a_dst  = (float*)   (ws + 44500000);
  float*    gm     = (float*)   (ws + 44700000);   // [gmax_s, gmax_d]
  float*    bmaxS  = (float*)   (ws + 44700032);   // per-tile maxes, 12.5 KB
  float*    bmaxD  = (float*)   (ws + 44712544);   // 12.5 KB

  // 1: coarse histogram (block-major) || weight transposes
  pre_k<<<NPB + 256, 256, 0, stream>>>(W_in, W_gat, W_h, BfA, BfB, BfC, ei, cpart);
  // 2: gemmA (h = leaky(x@W_in+b_in) -> f16, LDS-staged B) || coalesced bucket scan (1 block)
  gemm8_k<8,0,1,0><<<NBG + 1, 256, 0, stream>>>(x, nullptr, BfA, b_in,
      nullptr, hf, nullptr, nullptr, nullptr, nullptr, nullptr, nullptr, nullptr, cpart, nullptr);
  // 3: gemmB (g = h@W_gat -> f16 + a_src/a_dst + per-tile maxes) || bucket partition (128 blocks)
  gemm8_k<4,1,2,1><<<NBG + NPB, 256, 0, stream>>>(nullptr, hf, BfB, nullptr,
      nullptr, gf, att_src, att_dst, a_src, a_dst, bmaxS, bmaxD, ei, cpart, pairs);
  // 4: fine CSR per bucket (offs/degv/es) || global max reduce (1 block)
  fine_k<<<NBUCK + 1, 256, 0, stream>>>(pairs, cpart, offs, degv, es, bmaxS, bmaxD, gm);
  // 5: fused softmax + gather + normalize
  agg_k<<<6250, 256, 0, stream>>>(gf, offs, degv, es, a_src, a_dst, gm, b_gat, og);
  // 6: gemmC: y = leaky(og@W_h + b_h) @ W_out + b_out -> d_out fp32
  gemm8_k<4,2,0,1><<<NBG, 256, 0, stream>>>(nullptr, og, BfC, b_h,
      (float*)d_out, nullptr, W_out, b_out, nullptr, nullptr, nullptr, nullptr, nullptr, nullptr, nullptr);
}